// Round 2
// baseline (1001.102 us; speedup 1.0000x reference)
//
#include <hip/hip_runtime.h>

// Problem constants
#define BATCH 16384
#define DIM   256
#define KC    3000
#define KCPAD 3072

typedef __bf16   bf16x8  __attribute__((ext_vector_type(8)));
typedef float    floatx4 __attribute__((ext_vector_type(4)));
typedef _Float16 half8   __attribute__((ext_vector_type(8)));

// ---------------- normalize ----------------
__global__ __launch_bounds__(256) void normalize_rows(const float* __restrict__ x,
                                                      __bf16* __restrict__ out, int R) {
  __shared__ float s4[4];
  int row = blockIdx.x;
  int t = threadIdx.x;
  float v = 0.f;
  if (row < R) v = x[(size_t)row * DIM + t];
  float ss = v * v;
#pragma unroll
  for (int o = 32; o; o >>= 1) ss += __shfl_down(ss, o, 64);
  __syncthreads();
  if ((t & 63) == 0) s4[t >> 6] = ss;
  __syncthreads();
  float tot = s4[0] + s4[1] + s4[2] + s4[3];
  float inv = 1.f / fmaxf(sqrtf(tot), 1e-12f);
  out[(size_t)row * DIM + t] = (__bf16)(v * inv);
}

// ---------------- GEMM + fused colsum0 ----------------
// S[m][n] = sum_k A[m][k]*Bm[n][k]; S fp16 [16384 x 3072] (cols>=3000 = -3000).
// Also: csum0[n] += sum_m exp(20*S[m][n])   (valid cols only)
__global__ __launch_bounds__(256) void gemm_bf16(const __bf16* __restrict__ A,
                                                 const __bf16* __restrict__ Bm,
                                                 _Float16* __restrict__ S,
                                                 float* __restrict__ csum0) {
  __shared__ __align__(16) __bf16 As[128 * 32];
  __shared__ __align__(16) __bf16 Bs[128 * 32];
  const int tid = threadIdx.x;
  const int bm = blockIdx.x * 128;
  const int bn = blockIdx.y * 128;
  const int wid = tid >> 6;
  const int lane = tid & 63;
  const int wm = (wid >> 1) * 64;
  const int wn = (wid & 1) * 64;
  const int frow = lane & 15;
  const int fk = (lane >> 4) * 8;

  floatx4 acc[4][4] = {};

  for (int kt = 0; kt < DIM; kt += 32) {
    __syncthreads();
#pragma unroll
    for (int c = 0; c < 2; ++c) {
      int idx = tid + c * 256;
      int r = idx >> 2;
      int o = (idx & 3) * 8;
      *reinterpret_cast<int4*>(&As[r * 32 + o]) =
          *reinterpret_cast<const int4*>(A + (size_t)(bm + r) * DIM + kt + o);
      *reinterpret_cast<int4*>(&Bs[r * 32 + o]) =
          *reinterpret_cast<const int4*>(Bm + (size_t)(bn + r) * DIM + kt + o);
    }
    __syncthreads();
    bf16x8 af[4], bfr[4];
#pragma unroll
    for (int i = 0; i < 4; ++i)
      af[i] = *reinterpret_cast<const bf16x8*>(&As[(wm + i * 16 + frow) * 32 + fk]);
#pragma unroll
    for (int j = 0; j < 4; ++j)
      bfr[j] = *reinterpret_cast<const bf16x8*>(&Bs[(wn + j * 16 + frow) * 32 + fk]);
#pragma unroll
    for (int i = 0; i < 4; ++i)
#pragma unroll
      for (int j = 0; j < 4; ++j)
        acc[i][j] = __builtin_amdgcn_mfma_f32_16x16x32_bf16(af[i], bfr[j], acc[i][j], 0, 0, 0);
  }

  const int rgrp = (lane >> 4) * 4;   // C/D: row = (lane>>4)*4 + reg, col = lane&15
  const int cl = lane & 15;
#pragma unroll
  for (int j = 0; j < 4; ++j) {
    int colb = bn + wn + j * 16 + cl;
    bool valid = colb < KC;
    float csumj = 0.f;
#pragma unroll
    for (int i = 0; i < 4; ++i) {
#pragma unroll
      for (int r = 0; r < 4; ++r) {
        int rowb = bm + wm + i * 16 + rgrp + r;
        float sv = acc[i][j][r];
        S[(size_t)rowb * KCPAD + colb] = (_Float16)(valid ? sv : -3000.0f);
        csumj += __expf(20.f * sv);
      }
    }
    csumj = valid ? csumj : 0.f;
    csumj += __shfl_xor(csumj, 16, 64);
    csumj += __shfl_xor(csumj, 32, 64);
    if (lane < 16 && valid) atomicAdd(&csum0[colb], csumj);
  }
}

// ---------------- fused sinkhorn pass ----------------
// Reads csum_in -> u = 1/(K*csum_in) per col. Per row: rowtot = sum_k exp(20s)*u[k],
// v = 1/(B*rowtot) -> vout[row].
// DO_CSUM: csum_out[k] += sum_rows exp(20s)*v   (next iteration's colsum)
// !DO_CSUM (final): lse[row] = log(sum_k exp(10s))
template <bool DO_CSUM>
__global__ __launch_bounds__(384, 3) void sink_pass(const _Float16* __restrict__ S,
                                                    const float* __restrict__ csum_in,
                                                    float* __restrict__ csum_out,
                                                    float* __restrict__ vout,
                                                    float* __restrict__ lse) {
  __shared__ float wred[8][6];
  __shared__ float wred2[8][6];
  const int t = threadIdx.x;
  const int w = t >> 6;
  const int lane = t & 63;
  const int col0 = t * 8;
  const bool valid = col0 < KC;   // 3000 = 8*375: thread-uniform validity

  float u[8];
  {
    float4 c0 = *reinterpret_cast<const float4*>(&csum_in[col0]);
    float4 c1 = *reinterpret_cast<const float4*>(&csum_in[col0 + 4]);
    u[0] = valid ? 1.f / (3000.f * c0.x) : 0.f;
    u[1] = valid ? 1.f / (3000.f * c0.y) : 0.f;
    u[2] = valid ? 1.f / (3000.f * c0.z) : 0.f;
    u[3] = valid ? 1.f / (3000.f * c0.w) : 0.f;
    u[4] = valid ? 1.f / (3000.f * c1.x) : 0.f;
    u[5] = valid ? 1.f / (3000.f * c1.y) : 0.f;
    u[6] = valid ? 1.f / (3000.f * c1.z) : 0.f;
    u[7] = valid ? 1.f / (3000.f * c1.w) : 0.f;
  }

  const int r0 = blockIdx.x * 32;
  float creg[8] = {0.f, 0.f, 0.f, 0.f, 0.f, 0.f, 0.f, 0.f};

  for (int ch = 0; ch < 4; ++ch) {
    float e[8][8];
    // phase A: load 8 rows, wave-level partial reductions (no barriers between rows)
#pragma unroll
    for (int r = 0; r < 8; ++r) {
      int row = r0 + ch * 8 + r;
      half8 hv = *reinterpret_cast<const half8*>(&S[(size_t)row * KCPAD + col0]);
      float dot = 0.f, hs = 0.f;
#pragma unroll
      for (int j = 0; j < 8; ++j) {
        float s = (float)hv[j];
        if constexpr (DO_CSUM) {
          float ee = __expf(20.f * s);
          e[r][j] = ee;
          dot += ee * u[j];
        } else {
          float h = __expf(10.f * s);
          hs += h;
          dot += h * h * u[j];
        }
      }
#pragma unroll
      for (int o = 32; o; o >>= 1) dot += __shfl_down(dot, o, 64);
      if constexpr (!DO_CSUM) {
#pragma unroll
        for (int o = 32; o; o >>= 1) hs += __shfl_down(hs, o, 64);
      }
      if (lane == 0) {
        wred[r][w] = dot;
        if constexpr (!DO_CSUM) wred2[r][w] = hs;
      }
    }
    __syncthreads();
    // phase B
    if constexpr (DO_CSUM) {
#pragma unroll
      for (int r = 0; r < 8; ++r) {
        float tot = wred[r][0] + wred[r][1] + wred[r][2] + wred[r][3] + wred[r][4] + wred[r][5];
        float v = 1.f / (16384.f * tot);
#pragma unroll
        for (int j = 0; j < 8; ++j) creg[j] += e[r][j] * v;
      }
    }
    if (t < 8) {
      int row = r0 + ch * 8 + t;
      float tot = wred[t][0] + wred[t][1] + wred[t][2] + wred[t][3] + wred[t][4] + wred[t][5];
      vout[row] = 1.f / (16384.f * tot);
      if constexpr (!DO_CSUM) {
        float htot = wred2[t][0] + wred2[t][1] + wred2[t][2] + wred2[t][3] + wred2[t][4] + wred2[t][5];
        lse[row] = logf(htot);
      }
    }
    __syncthreads();
  }

  if constexpr (DO_CSUM) {
    if (valid) {
#pragma unroll
      for (int j = 0; j < 8; ++j) atomicAdd(&csum_out[col0 + j], creg[j]);
    }
  }
}

// ---------------- fused KL (both losses) ----------------
__global__ __launch_bounds__(384, 4) void kl_kernel(
    const _Float16* __restrict__ Sk, const _Float16* __restrict__ Sq,
    const float* __restrict__ csK2, const float* __restrict__ csQ2,
    const float* __restrict__ vk, const float* __restrict__ vq,
    const float* __restrict__ lseq, const float* __restrict__ lsek,
    float* __restrict__ accOut) {
  __shared__ float rc[32][4];
  __shared__ float s6[6];
  const int t = threadIdx.x;
  const int col0 = t * 8;
  const bool valid = col0 < KC;
  const float logB = 9.704060528f;  // log(16384)

  float uk[8], luk[8], uq[8], luq[8];
  {
    float4 a0 = *reinterpret_cast<const float4*>(&csK2[col0]);
    float4 a1 = *reinterpret_cast<const float4*>(&csK2[col0 + 4]);
    float4 b0 = *reinterpret_cast<const float4*>(&csQ2[col0]);
    float4 b1 = *reinterpret_cast<const float4*>(&csQ2[col0 + 4]);
    float ca[8] = {a0.x, a0.y, a0.z, a0.w, a1.x, a1.y, a1.z, a1.w};
    float cb[8] = {b0.x, b0.y, b0.z, b0.w, b1.x, b1.y, b1.z, b1.w};
#pragma unroll
    for (int j = 0; j < 8; ++j) {
      uk[j] = valid ? 1.f / (3000.f * ca[j]) : 0.f;
      uq[j] = valid ? 1.f / (3000.f * cb[j]) : 0.f;
      luk[j] = logf(fmaxf(uk[j], 1e-30f));
      luq[j] = logf(fmaxf(uq[j], 1e-30f));
    }
  }

  const int r0 = blockIdx.x * 32;
  if (t < 32) {
    int r = r0 + t;
    float a = vk[r], b = vq[r];
    rc[t][0] = 16384.f * a;
    rc[t][1] = logB + logf(a) + lseq[r];
    rc[t][2] = 16384.f * b;
    rc[t][3] = logB + logf(b) + lsek[r];
  }
  __syncthreads();

  float acc = 0.f;
  for (int r = 0; r < 32; ++r) {
    size_t base = (size_t)(r0 + r) * KCPAD + col0;
    half8 hk = *reinterpret_cast<const half8*>(&Sk[base]);
    half8 hq = *reinterpret_cast<const half8*>(&Sq[base]);
    float b1 = rc[r][0], A1 = rc[r][1], b2 = rc[r][2], A2 = rc[r][3];
#pragma unroll
    for (int j = 0; j < 8; ++j) {
      float sk = (float)hk[j];
      float sq = (float)hq[j];
      float ek = __expf(20.f * sk);
      float eq = __expf(20.f * sq);
      acc += ek * uk[j] * b1 * (A1 + luk[j] + 20.f * sk - 10.f * sq)
           + eq * uq[j] * b2 * (A2 + luq[j] + 20.f * sq - 10.f * sk);
    }
  }

#pragma unroll
  for (int o = 32; o; o >>= 1) acc += __shfl_down(acc, o, 64);
  __syncthreads();
  if ((t & 63) == 0) s6[t >> 6] = acc;
  __syncthreads();
  if (t == 0) {
    float tot = s6[0] + s6[1] + s6[2] + s6[3] + s6[4] + s6[5];
    atomicAdd(accOut, tot);
  }
}

__global__ void finalize_k(const float* __restrict__ acc, float* __restrict__ out) {
  out[0] = acc[0] * (1.f / 32768.f);  // /(2*B)
}

extern "C" void kernel_launch(void* const* d_in, const int* in_sizes, int n_in,
                              void* d_out, int out_size, void* d_ws, size_t ws_size,
                              hipStream_t stream) {
  const float* q = (const float*)d_in[0];
  const float* k = (const float*)d_in[1];
  const float* c = (const float*)d_in[2];
  float* out = (float*)d_out;

  char* ws = (char*)d_ws;
  // layout (bytes):
  __bf16* nk = (__bf16*)(ws);                         // 8,388,608
  __bf16* nc = (__bf16*)(ws + 8388608);               // 1,572,864
  _Float16* Sq = (_Float16*)(ws + 9961472);           // 16384*3072*2 = 100,663,296
  _Float16* Sk = (_Float16*)(ws + 110624768);         // 100,663,296
  __bf16* nq = (__bf16*)(ws + 110624768);             // aliased into Sk: dead after GEMM1
  float* fbase = (float*)(ws + 211288064);
  float* csK0 = fbase;          // 3072
  float* csK1 = fbase + 3072;   // 3072
  float* csK2 = fbase + 6144;   // 3072
  float* csQ0 = fbase + 9216;   // 3072
  float* csQ1 = fbase + 12288;  // 3072
  float* csQ2 = fbase + 15360;  // 3072
  float* accv = fbase + 18432;  // 16
  float* vk   = fbase + 18448;  // 16384
  float* vq   = fbase + 34832;  // 16384
  float* lseq = fbase + 51216;  // 16384
  float* lsek = fbase + 67600;  // 16384

  // zero all atomic accumulators (csums + accv) in one memset
  hipMemsetAsync(fbase, 0, (18432 + 16) * sizeof(float), stream);

  normalize_rows<<<16384, 256, 0, stream>>>(q, nq, BATCH);
  normalize_rows<<<16384, 256, 0, stream>>>(k, nk, BATCH);
  normalize_rows<<<3072, 256, 0, stream>>>(c, nc, KC);

  dim3 gg(BATCH / 128, KCPAD / 128);
  gemm_bf16<<<gg, 256, 0, stream>>>(nq, nc, Sq, csQ0);
  gemm_bf16<<<gg, 256, 0, stream>>>(nk, nc, Sk, csK0);  // overwrites nq (dead)

  // sinkhorn: 3 fused passes per matrix
  sink_pass<true ><<<512, 384, 0, stream>>>(Sk, csK0, csK1, vk, nullptr);
  sink_pass<true ><<<512, 384, 0, stream>>>(Sk, csK1, csK2, vk, nullptr);
  sink_pass<false><<<512, 384, 0, stream>>>(Sk, csK2, nullptr, vk, lsek);

  sink_pass<true ><<<512, 384, 0, stream>>>(Sq, csQ0, csQ1, vq, nullptr);
  sink_pass<true ><<<512, 384, 0, stream>>>(Sq, csQ1, csQ2, vq, nullptr);
  sink_pass<false><<<512, 384, 0, stream>>>(Sq, csQ2, nullptr, vq, lseq);

  kl_kernel<<<512, 384, 0, stream>>>(Sk, Sq, csK2, csQ2, vk, vq, lseq, lsek, accv);
  finalize_k<<<1, 1, 0, stream>>>(accv, out);
}

// Round 3
// 877.758 us; speedup vs baseline: 1.1405x; 1.1405x over previous
//
#include <hip/hip_runtime.h>

// Problem constants
#define BATCH 16384
#define DIM   256
#define KC    3000
#define KCPAD 3072

typedef __bf16   bf16x8  __attribute__((ext_vector_type(8)));
typedef float    floatx4 __attribute__((ext_vector_type(4)));
typedef _Float16 half8   __attribute__((ext_vector_type(8)));

// ---------------- normalize ----------------
__global__ __launch_bounds__(256) void normalize_rows(const float* __restrict__ x,
                                                      __bf16* __restrict__ out, int R) {
  __shared__ float s4[4];
  int row = blockIdx.x;
  int t = threadIdx.x;
  float v = 0.f;
  if (row < R) v = x[(size_t)row * DIM + t];
  float ss = v * v;
#pragma unroll
  for (int o = 32; o; o >>= 1) ss += __shfl_down(ss, o, 64);
  __syncthreads();
  if ((t & 63) == 0) s4[t >> 6] = ss;
  __syncthreads();
  float tot = s4[0] + s4[1] + s4[2] + s4[3];
  float inv = 1.f / fmaxf(sqrtf(tot), 1e-12f);
  out[(size_t)row * DIM + t] = (__bf16)(v * inv);
}

// ---------------- GEMM + fused colsum0 ----------------
// S[m][n] = sum_k A[m][k]*Bm[n][k]; S fp16 [16384 x 3072] (cols>=3000 = -3000).
// Also: csum0[n] += sum_m exp(20*S[m][n])   (valid cols only)
__global__ __launch_bounds__(256) void gemm_bf16(const __bf16* __restrict__ A,
                                                 const __bf16* __restrict__ Bm,
                                                 _Float16* __restrict__ S,
                                                 float* __restrict__ csum0) {
  __shared__ __align__(16) __bf16 As[128 * 32];
  __shared__ __align__(16) __bf16 Bs[128 * 32];
  const int tid = threadIdx.x;
  const int bm = blockIdx.x * 128;
  const int bn = blockIdx.y * 128;
  const int wid = tid >> 6;
  const int lane = tid & 63;
  const int wm = (wid >> 1) * 64;
  const int wn = (wid & 1) * 64;
  const int frow = lane & 15;
  const int fk = (lane >> 4) * 8;

  floatx4 acc[4][4] = {};

  for (int kt = 0; kt < DIM; kt += 32) {
    __syncthreads();
#pragma unroll
    for (int c = 0; c < 2; ++c) {
      int idx = tid + c * 256;
      int r = idx >> 2;
      int o = (idx & 3) * 8;
      *reinterpret_cast<int4*>(&As[r * 32 + o]) =
          *reinterpret_cast<const int4*>(A + (size_t)(bm + r) * DIM + kt + o);
      *reinterpret_cast<int4*>(&Bs[r * 32 + o]) =
          *reinterpret_cast<const int4*>(Bm + (size_t)(bn + r) * DIM + kt + o);
    }
    __syncthreads();
    bf16x8 af[4], bfr[4];
#pragma unroll
    for (int i = 0; i < 4; ++i)
      af[i] = *reinterpret_cast<const bf16x8*>(&As[(wm + i * 16 + frow) * 32 + fk]);
#pragma unroll
    for (int j = 0; j < 4; ++j)
      bfr[j] = *reinterpret_cast<const bf16x8*>(&Bs[(wn + j * 16 + frow) * 32 + fk]);
#pragma unroll
    for (int i = 0; i < 4; ++i)
#pragma unroll
      for (int j = 0; j < 4; ++j)
        acc[i][j] = __builtin_amdgcn_mfma_f32_16x16x32_bf16(af[i], bfr[j], acc[i][j], 0, 0, 0);
  }

  const int rgrp = (lane >> 4) * 4;   // C/D: row = (lane>>4)*4 + reg, col = lane&15
  const int cl = lane & 15;
#pragma unroll
  for (int j = 0; j < 4; ++j) {
    int colb = bn + wn + j * 16 + cl;
    bool valid = colb < KC;
    float csumj = 0.f;
#pragma unroll
    for (int i = 0; i < 4; ++i) {
#pragma unroll
      for (int r = 0; r < 4; ++r) {
        int rowb = bm + wm + i * 16 + rgrp + r;
        float sv = acc[i][j][r];
        S[(size_t)rowb * KCPAD + colb] = (_Float16)(valid ? sv : -3000.0f);
        csumj += __expf(20.f * sv);
      }
    }
    csumj = valid ? csumj : 0.f;
    csumj += __shfl_xor(csumj, 16, 64);
    csumj += __shfl_xor(csumj, 32, 64);
    if (lane < 16 && valid) atomicAdd(&csum0[colb], csumj);
  }
}

// ---------------- fused sinkhorn pass (row-norm of next iter folded in) ----------------
// u = 1/(K*csum_in). Per row: tot = sum_k exp(20s)*u[k]; v = 1/(B*tot);
// csum_out[k] += sum_rows exp(20s)*v.
// Caches raw fp16 across the barrier (32 VGPRs), recomputes exp in phase B -> no spill.
__global__ __launch_bounds__(384, 2) void sink_pass(const _Float16* __restrict__ S,
                                                    const float* __restrict__ csum_in,
                                                    float* __restrict__ csum_out) {
  __shared__ float wred[8][6];
  const int t = threadIdx.x;
  const int w = t >> 6;
  const int lane = t & 63;
  const int col0 = t * 8;
  const bool valid = col0 < KC;   // 3000 = 8*375: thread-uniform validity

  float u[8];
  {
    float4 c0 = *reinterpret_cast<const float4*>(&csum_in[col0]);
    float4 c1 = *reinterpret_cast<const float4*>(&csum_in[col0 + 4]);
    float cs[8] = {c0.x, c0.y, c0.z, c0.w, c1.x, c1.y, c1.z, c1.w};
#pragma unroll
    for (int j = 0; j < 8; ++j) u[j] = valid ? 1.f / (3000.f * cs[j]) : 0.f;
  }

  const int r0 = blockIdx.x * 32;
  float creg[8] = {0.f, 0.f, 0.f, 0.f, 0.f, 0.f, 0.f, 0.f};

  for (int ch = 0; ch < 4; ++ch) {
    half8 hv[8];
#pragma unroll
    for (int r = 0; r < 8; ++r)
      hv[r] = *reinterpret_cast<const half8*>(&S[(size_t)(r0 + ch * 8 + r) * KCPAD + col0]);
#pragma unroll
    for (int r = 0; r < 8; ++r) {
      float dot = 0.f;
#pragma unroll
      for (int j = 0; j < 8; ++j) dot += __expf(20.f * (float)hv[r][j]) * u[j];
#pragma unroll
      for (int o = 32; o; o >>= 1) dot += __shfl_down(dot, o, 64);
      if (lane == 0) wred[r][w] = dot;
    }
    __syncthreads();
#pragma unroll
    for (int r = 0; r < 8; ++r) {
      float tot = wred[r][0] + wred[r][1] + wred[r][2] + wred[r][3] + wred[r][4] + wred[r][5];
      float v = 1.f / (16384.f * tot);
#pragma unroll
      for (int j = 0; j < 8; ++j) creg[j] += __expf(20.f * (float)hv[r][j]) * v;
    }
    __syncthreads();
  }

  if (valid) {
#pragma unroll
    for (int j = 0; j < 8; ++j) atomicAdd(&csum_out[col0 + j], creg[j]);
  }
}

// ---------------- fused final-iteration + KL (both losses), single streaming pass ----
// Per row b:
//   loss1 += log(sum exp(10 sq)) - log(Dk) + Ek/Dk,   Dk = sum ek*uk,
//   Ek = sum ek*(wk + uk*(20 sk - 10 sq)),  wk = uk*log(uk),  ek = exp(20 sk)
//   loss2: symmetric (q<->k).
// No per-row barrier: each wave reduces its partials and writes 6 floats/row to LDS.
__global__ __launch_bounds__(384, 2) void kl_kernel(
    const _Float16* __restrict__ Sk, const _Float16* __restrict__ Sq,
    const float* __restrict__ csK2, const float* __restrict__ csQ2,
    float* __restrict__ accOut) {
  __shared__ float wred[32][6][6];  // [row][wave][quantity]
  const int t = threadIdx.x;
  const int w = t >> 6;
  const int lane = t & 63;
  const int col0 = t * 8;
  const bool valid = col0 < KC;

  float uk[8], wk[8], uq[8], wq[8];
  {
    float4 a0 = *reinterpret_cast<const float4*>(&csK2[col0]);
    float4 a1 = *reinterpret_cast<const float4*>(&csK2[col0 + 4]);
    float4 b0 = *reinterpret_cast<const float4*>(&csQ2[col0]);
    float4 b1 = *reinterpret_cast<const float4*>(&csQ2[col0 + 4]);
    float ca[8] = {a0.x, a0.y, a0.z, a0.w, a1.x, a1.y, a1.z, a1.w};
    float cb[8] = {b0.x, b0.y, b0.z, b0.w, b1.x, b1.y, b1.z, b1.w};
#pragma unroll
    for (int j = 0; j < 8; ++j) {
      float ukj = valid ? 1.f / (3000.f * ca[j]) : 0.f;
      float uqj = valid ? 1.f / (3000.f * cb[j]) : 0.f;
      uk[j] = ukj; uq[j] = uqj;
      wk[j] = valid ? ukj * logf(ukj) : 0.f;
      wq[j] = valid ? uqj * logf(uqj) : 0.f;
    }
  }

  const int r0 = blockIdx.x * 32;
  for (int r = 0; r < 32; ++r) {
    size_t base = (size_t)(r0 + r) * KCPAD + col0;
    half8 hk = *reinterpret_cast<const half8*>(&Sk[base]);
    half8 hq = *reinterpret_cast<const half8*>(&Sq[base]);
    float Dk = 0.f, Ek = 0.f, hks = 0.f, Dq = 0.f, Eq = 0.f, hqs = 0.f;
#pragma unroll
    for (int j = 0; j < 8; ++j) {
      float sk = (float)hk[j], sq = (float)hq[j];
      float tk = __expf(10.f * sk), tq = __expf(10.f * sq);
      float ek = tk * tk, eq = tq * tq;
      hks += tk; hqs += tq;
      Dk += ek * uk[j];
      Dq += eq * uq[j];
      Ek += ek * (wk[j] + uk[j] * (20.f * sk - 10.f * sq));
      Eq += eq * (wq[j] + uq[j] * (20.f * sq - 10.f * sk));
    }
#pragma unroll
    for (int o = 32; o; o >>= 1) {
      Dk += __shfl_down(Dk, o, 64);  Ek += __shfl_down(Ek, o, 64);  hks += __shfl_down(hks, o, 64);
      Dq += __shfl_down(Dq, o, 64);  Eq += __shfl_down(Eq, o, 64);  hqs += __shfl_down(hqs, o, 64);
    }
    if (lane == 0) {
      wred[r][w][0] = Dk; wred[r][w][1] = Ek; wred[r][w][2] = hks;
      wred[r][w][3] = Dq; wred[r][w][4] = Eq; wred[r][w][5] = hqs;
    }
  }
  __syncthreads();

  float contrib = 0.f;
  if (t < 32) {
    float v[6] = {0.f, 0.f, 0.f, 0.f, 0.f, 0.f};
#pragma unroll
    for (int ww = 0; ww < 6; ++ww)
#pragma unroll
      for (int qq = 0; qq < 6; ++qq) v[qq] += wred[t][ww][qq];
    contrib = logf(v[5]) - logf(v[0]) + v[1] / v[0]
            + logf(v[2]) - logf(v[3]) + v[4] / v[3];
  }
  if (w == 0) {
#pragma unroll
    for (int o = 32; o; o >>= 1) contrib += __shfl_down(contrib, o, 64);
    if (lane == 0) atomicAdd(accOut, contrib);
  }
}

__global__ void finalize_k(const float* __restrict__ acc, float* __restrict__ out) {
  out[0] = acc[0] * (1.f / 32768.f);  // /(2*B)
}

extern "C" void kernel_launch(void* const* d_in, const int* in_sizes, int n_in,
                              void* d_out, int out_size, void* d_ws, size_t ws_size,
                              hipStream_t stream) {
  const float* q = (const float*)d_in[0];
  const float* k = (const float*)d_in[1];
  const float* c = (const float*)d_in[2];
  float* out = (float*)d_out;

  char* ws = (char*)d_ws;
  __bf16* nk = (__bf16*)(ws);                         // 8,388,608
  __bf16* nc = (__bf16*)(ws + 8388608);               // 1,572,864
  _Float16* Sq = (_Float16*)(ws + 9961472);           // 16384*3072*2 = 100,663,296
  _Float16* Sk = (_Float16*)(ws + 110624768);         // 100,663,296
  __bf16* nq = (__bf16*)(ws + 110624768);             // aliased into Sk: dead after GEMM1
  float* fbase = (float*)(ws + 211288064);
  float* csK0 = fbase;          // 3072
  float* csK1 = fbase + 3072;   // 3072
  float* csK2 = fbase + 6144;   // 3072
  float* csQ0 = fbase + 9216;   // 3072
  float* csQ1 = fbase + 12288;  // 3072
  float* csQ2 = fbase + 15360;  // 3072
  float* accv = fbase + 18432;  // 16

  hipMemsetAsync(fbase, 0, (18432 + 16) * sizeof(float), stream);

  normalize_rows<<<16384, 256, 0, stream>>>(q, nq, BATCH);
  normalize_rows<<<16384, 256, 0, stream>>>(k, nk, BATCH);
  normalize_rows<<<3072, 256, 0, stream>>>(c, nc, KC);

  dim3 gg(BATCH / 128, KCPAD / 128);
  gemm_bf16<<<gg, 256, 0, stream>>>(nq, nc, Sq, csQ0);
  gemm_bf16<<<gg, 256, 0, stream>>>(nk, nc, Sk, csK0);  // overwrites nq (dead)

  // sinkhorn: 2 fused passes per matrix; 3rd iteration folds into kl_kernel
  sink_pass<<<512, 384, 0, stream>>>(Sk, csK0, csK1);
  sink_pass<<<512, 384, 0, stream>>>(Sk, csK1, csK2);
  sink_pass<<<512, 384, 0, stream>>>(Sq, csQ0, csQ1);
  sink_pass<<<512, 384, 0, stream>>>(Sq, csQ1, csQ2);

  kl_kernel<<<512, 384, 0, stream>>>(Sk, Sq, csK2, csQ2, accv);
  finalize_k<<<1, 1, 0, stream>>>(accv, out);
}